// Round 5
// baseline (298.490 us; speedup 1.0000x reference)
//
#include <hip/hip_runtime.h>
#include <hip/hip_bf16.h>
#include <stdint.h>

#define BATCH 4
#define TLEN  4096
#define DDIM  1024
#define NCOND 512
#define LDIM  768
#define NHEAD 8
#define HD    128

typedef __bf16 bf16x8 __attribute__((ext_vector_type(8)));
typedef float  f32x4  __attribute__((ext_vector_type(4)));
typedef unsigned short us8 __attribute__((ext_vector_type(8)));

__device__ __forceinline__ unsigned short f2b(float f) {
    unsigned int u = __builtin_bit_cast(unsigned int, f);
    unsigned int r = (u + 0x7fffu + ((u >> 16) & 1u)) >> 16;
    return (unsigned short)r;
}
__device__ __forceinline__ float b2f(unsigned short s) {
    unsigned int u = ((unsigned int)s) << 16;
    return __builtin_bit_cast(float, u);
}

__device__ __forceinline__ void gl2lds(const void* g, void* l) {
    __builtin_amdgcn_global_load_lds(
        (const __attribute__((address_space(1))) void*)(uintptr_t)g,
        (__attribute__((address_space(3))) void*)(uintptr_t)l,
        16, 0, 0);
}

// Swizzle convention ("A-swizzle") for bf16 GEMM operands in GLOBAL memory:
// within each 32-col (64 B) window of row r, logical 16-B chunk c is stored
// at position c ^ ((r>>1)&3).  Staging loads LINEAR positions (so LDS
// position p holds logical p ^ s); fragment reads XOR with s to recover
// logical chunk quad.  Net effect: frag ds_read_b128 is 2-way (free).

// ---------------- fused LN stats + apply -> bf16 (A-swizzled) ----------------
__global__ __launch_bounds__(128) void ln_apply_sw(const float* __restrict__ x,
    const float* __restrict__ g, const float* __restrict__ bb,
    unsigned short* __restrict__ o, int rowlen)
{
    long r = blockIdx.x;
    const float* p = x + r * (long)rowlen;
    int tid = threadIdx.x;
    int c = tid * 8;
    bool act = c < rowlen;
    float4 v0 = make_float4(0.f, 0.f, 0.f, 0.f), v1 = v0;
    if (act) { v0 = *(const float4*)(p + c); v1 = *(const float4*)(p + c + 4); }
    float s  = v0.x + v0.y + v0.z + v0.w + v1.x + v1.y + v1.z + v1.w;
    float ss = v0.x * v0.x + v0.y * v0.y + v0.z * v0.z + v0.w * v0.w
             + v1.x * v1.x + v1.y * v1.y + v1.z * v1.z + v1.w * v1.w;
#pragma unroll
    for (int off = 32; off; off >>= 1) {
        s  += __shfl_xor(s,  off, 64);
        ss += __shfl_xor(ss, off, 64);
    }
    __shared__ float sh[4];
    __shared__ float mu_s, rs_s;
    int wid = tid >> 6, lane = tid & 63;
    if (lane == 0) { sh[wid * 2] = s; sh[wid * 2 + 1] = ss; }
    __syncthreads();
    if (tid == 0) {
        float S = sh[0] + sh[2], SS = sh[1] + sh[3];
        float mu = S / rowlen;
        float var = SS / rowlen - mu * mu;
        mu_s = mu; rs_s = rsqrtf(fmaxf(var, 0.f) + 1e-5f);
    }
    __syncthreads();
    if (act) {
        float mu = mu_s, rs = rs_s;
        float4 g0 = *(const float4*)(g + c),  g1 = *(const float4*)(g + c + 4);
        float4 b0 = *(const float4*)(bb + c), b1 = *(const float4*)(bb + c + 4);
        us8 ov;
        ov[0] = f2b((v0.x - mu) * rs * g0.x + b0.x);
        ov[1] = f2b((v0.y - mu) * rs * g0.y + b0.y);
        ov[2] = f2b((v0.z - mu) * rs * g0.z + b0.z);
        ov[3] = f2b((v0.w - mu) * rs * g0.w + b0.w);
        ov[4] = f2b((v1.x - mu) * rs * g1.x + b1.x);
        ov[5] = f2b((v1.y - mu) * rs * g1.y + b1.y);
        ov[6] = f2b((v1.z - mu) * rs * g1.z + b1.z);
        ov[7] = f2b((v1.w - mu) * rs * g1.w + b1.w);
        int wnd = c & ~31;
        int ch  = ((c >> 3) & 3) ^ ((int)(r >> 1) & 3);
        *(us8*)(o + r * (long)rowlen + wnd + ch * 8) = ov;
    }
}

// ---------------- W [K,N] f32 -> Wt [N,K] bf16, A-swizzled, 3-in-1 ----------
__global__ __launch_bounds__(256) void wtrans3(const float* __restrict__ Wq,
    const float* __restrict__ Wk, const float* __restrict__ Wv,
    unsigned short* __restrict__ wqT, unsigned short* __restrict__ wkvT)
{
    int z = blockIdx.z;
    const float* W = (z == 0) ? Wq : ((z == 1) ? Wk : Wv);
    int K = (z == 0) ? 1024 : 768;
    unsigned short* Wt = (z == 0) ? wqT : ((z == 1) ? wkvT : wkvT + 768 * 1024);
    int k0 = blockIdx.y * 32;
    if (k0 >= K) return;
    __shared__ float t[32][33];
    int n0 = blockIdx.x * 32;
    int tx = threadIdx.x & 31, ty = threadIdx.x >> 5;
#pragma unroll
    for (int i = 0; i < 4; i++)
        t[ty + i * 8][tx] = W[(long)(k0 + ty + i * 8) * 1024 + n0 + tx];
    __syncthreads();
    int k = k0 + tx;
    int wnd = k & ~31;
#pragma unroll
    for (int i = 0; i < 4; i++) {
        int n = n0 + ty + i * 8;
        int k2 = wnd + ((((k >> 3) & 3) ^ ((n >> 1) & 3)) << 3) + (k & 7);
        Wt[(long)n * K + k2] = f2b(t[tx][ty + i * 8]);
    }
}

// ---------------- bf16 MFMA GEMM (kv projection), swizzled operands --------
template <int MB, bool OBF>
__global__ __launch_bounds__(256) void gemm_bf16(
    const unsigned short* __restrict__ A, int lda,
    const unsigned short* __restrict__ Bt, int ldb,
    const float* __restrict__ bias0, const float* __restrict__ bias1,
    void* __restrict__ Cv, int ldc, int K, int zdiv,
    long long Bi, long long Ci)
{
    constexpr int IM = MB / 32;
    int zi = blockIdx.z % zdiv;
    const unsigned short* Ap = A;
    const unsigned short* Bp = Bt + zi * Bi;
    const float* bias = (zi & 1) ? bias1 : bias0;
    long coff = zi * Ci;

    int m0 = blockIdx.y * MB, n0 = blockIdx.x * 128;
    int tid = threadIdx.x, lane = tid & 63, wid = tid >> 6;
    int l16 = lane & 15, quad = lane >> 4;
    int mw = (wid & 1) * (MB / 2), nw = (wid >> 1) << 6;

    __shared__ unsigned short As[MB * 32];
    __shared__ unsigned short Bs[128 * 32];

    f32x4 acc[IM][4];
#pragma unroll
    for (int i = 0; i < IM; i++)
#pragma unroll
        for (int j = 0; j < 4; j++) { acc[i][j][0] = 0.f; acc[i][j][1] = 0.f; acc[i][j][2] = 0.f; acc[i][j][3] = 0.f; }

    // staging loads LINEAR global positions; global buffer is pre-swizzled
    int arow = m0 + (tid >> 2);
    const unsigned short* ag = Ap + (long)arow * lda + (tid & 3) * 8;
    int brow = n0 + (tid >> 2);
    const unsigned short* bg = Bp + (long)brow * ldb + (tid & 3) * 8;
    unsigned short* asw = As + wid * 512;
    unsigned short* bsw = Bs + wid * 512;
    long a64 = (long)64 * lda, b64 = (long)64 * ldb;

    for (int kt = 0; kt < K; kt += 32) {
        gl2lds(ag + kt, asw);
        if (MB == 128) gl2lds(ag + a64 + kt, asw + 2048);
        gl2lds(bg + kt,       bsw);
        gl2lds(bg + b64 + kt, bsw + 2048);
        __syncthreads();
        bf16x8 af[IM], bfr[4];
#pragma unroll
        for (int i = 0; i < IM; i++) {
            int ar = mw + i * 16 + l16;
            af[i] = *(const bf16x8*)&As[ar * 32 + ((quad ^ ((ar >> 1) & 3)) << 3)];
        }
#pragma unroll
        for (int j = 0; j < 4; j++) {
            int br = nw + j * 16 + l16;
            bfr[j] = *(const bf16x8*)&Bs[br * 32 + ((quad ^ ((br >> 1) & 3)) << 3)];
        }
#pragma unroll
        for (int i = 0; i < IM; i++)
#pragma unroll
            for (int j = 0; j < 4; j++)
                acc[i][j] = __builtin_amdgcn_mfma_f32_16x16x32_bf16(af[i], bfr[j], acc[i][j], 0, 0, 0);
        __syncthreads();
    }

#pragma unroll
    for (int j = 0; j < 4; j++) {
        int col = n0 + nw + j * 16 + l16;
        float bvv = bias ? bias[col] : 0.f;
#pragma unroll
        for (int i = 0; i < IM; i++) {
            int row0 = m0 + mw + i * 16 + (quad << 2);
#pragma unroll
            for (int r = 0; r < 4; r++) {
                float val = acc[i][j][r] + bvv;
                long idx = coff + (long)(row0 + r) * ldc + col;
                if (OBF) ((unsigned short*)Cv)[idx] = f2b(val);
                else     ((float*)Cv)[idx] = val;
            }
        }
    }
}

// ---------------- fused q-path: proj + bias + head-softmax + @ctx -> out ----
// LDS 51,200 B -> 3 blocks/CU.  Pb written in two 64-col halves.
__global__ __launch_bounds__(256, 3) void qfused(
    const unsigned short* __restrict__ xn,   // [16384,1024] bf16 A-swizzled
    const unsigned short* __restrict__ wqT,  // [1024,1024]  bf16 A-swizzled
    const float* __restrict__ bq,
    const unsigned short* __restrict__ ctxT, // [32][128(vv)][128(kk)] bf16 linear
    float* __restrict__ out)                 // [16384,1024] f32
{
    __shared__ unsigned short buf[25600];        // 51,200 B
    unsigned short* As = buf;                    // [0, 8192) B   stage-1
    unsigned short* Bs = buf + 4096;             // [8192,16384) B stage-1
    unsigned short* Pb = buf;                    // [0, 16384) B  stage-2 (64-col half)
    unsigned short* Cx = buf + 8192;             // [16384,49152) B
    float* redM = (float*)(buf + 24576);         // [49152,50176) B  [2][128]
    float* redS = redM + 256;                    // [50176,51200) B  [2][128]

    int head = blockIdx.y;
    int m0 = blockIdx.x * 128;
    int b  = m0 >> 12;
    int tid = threadIdx.x, lane = tid & 63, wid = tid >> 6;
    int l16 = lane & 15, quad = lane >> 4;
    int mw = (wid & 1) << 6, nw = (wid >> 1) << 6;
    int ch = wid >> 1;

    // stage ctx tile -> Cx, swizzled: chunk c at c ^ (vv&15)
    {
        const unsigned short* cg = ctxT + ((long)(b * NHEAD + head) << 14);
#pragma unroll
        for (int pass = 0; pass < 8; pass++) {
            int idx = pass * 2048 + tid * 8;
            int vv = idx >> 7, kkc = (idx & 127) >> 3;
            *(bf16x8*)&Cx[vv * 128 + ((kkc ^ (vv & 15)) << 3)] = *(const bf16x8*)&cg[idx];
        }
    }

    f32x4 acc[4][4];
#pragma unroll
    for (int i = 0; i < 4; i++)
#pragma unroll
        for (int j = 0; j < 4; j++) { acc[i][j][0] = 0.f; acc[i][j][1] = 0.f; acc[i][j][2] = 0.f; acc[i][j][3] = 0.f; }

    // staging loads LINEAR global positions; xn/wqT are pre-swizzled
    int arow = m0 + (tid >> 2);
    const unsigned short* ag = xn + (long)arow * DDIM + (tid & 3) * 8;
    int brow = head * 128 + (tid >> 2);
    const unsigned short* bg = wqT + (long)brow * DDIM + (tid & 3) * 8;
    unsigned short* asw = As + wid * 512;
    unsigned short* bsw = Bs + wid * 512;
    const long a64 = 64L * DDIM;

    for (int kt = 0; kt < DDIM; kt += 32) {
        gl2lds(ag + kt,        asw);
        gl2lds(ag + a64 + kt,  asw + 2048);
        gl2lds(bg + kt,        bsw);
        gl2lds(bg + a64 + kt,  bsw + 2048);
        __syncthreads();
        bf16x8 af[4], bfr[4];
#pragma unroll
        for (int i = 0; i < 4; i++) {
            int ar = mw + i * 16 + l16;
            af[i] = *(const bf16x8*)&As[ar * 32 + ((quad ^ ((ar >> 1) & 3)) << 3)];
        }
#pragma unroll
        for (int j = 0; j < 4; j++) {
            int br = nw + j * 16 + l16;
            bfr[j] = *(const bf16x8*)&Bs[br * 32 + ((quad ^ ((br >> 1) & 3)) << 3)];
        }
#pragma unroll
        for (int i = 0; i < 4; i++)
#pragma unroll
            for (int j = 0; j < 4; j++)
                acc[i][j] = __builtin_amdgcn_mfma_f32_16x16x32_bf16(af[i], bfr[j], acc[i][j], 0, 0, 0);
        __syncthreads();
    }

    // ---- bias ----
    float bvv[4];
#pragma unroll
    for (int j = 0; j < 4; j++) bvv[j] = bq[head * 128 + nw + j * 16 + l16];
#pragma unroll
    for (int i = 0; i < 4; i++)
#pragma unroll
        for (int j = 0; j < 4; j++)
#pragma unroll
            for (int r = 0; r < 4; r++) acc[i][j][r] += bvv[j];

    // ---- row max (this wave's 64-col half) ----
    float mx[4][4];
#pragma unroll
    for (int i = 0; i < 4; i++)
#pragma unroll
        for (int r = 0; r < 4; r++) {
            float m = fmaxf(fmaxf(acc[i][0][r], acc[i][1][r]), fmaxf(acc[i][2][r], acc[i][3][r]));
            mx[i][r] = m;
        }
#pragma unroll
    for (int off = 1; off < 16; off <<= 1)
#pragma unroll
        for (int i = 0; i < 4; i++)
#pragma unroll
            for (int r = 0; r < 4; r++)
                mx[i][r] = fmaxf(mx[i][r], __shfl_xor(mx[i][r], off, 64));
    if (l16 == 0) {
#pragma unroll
        for (int i = 0; i < 4; i++)
#pragma unroll
            for (int r = 0; r < 4; r++)
                redM[ch * 128 + mw + i * 16 + quad * 4 + r] = mx[i][r];
    }
    __syncthreads();

    // ---- exp (bf16-rounded) -> packed regs; partial sums ----
    unsigned int ep[4][4][2];
    float sm[4][4];
#pragma unroll
    for (int i = 0; i < 4; i++)
#pragma unroll
        for (int r = 0; r < 4; r++) {
            int row = mw + i * 16 + quad * 4 + r;
            float M = fmaxf(redM[row], redM[128 + row]);
            float s = 0.f;
#pragma unroll
            for (int j = 0; j < 4; j++) {
                unsigned short eb = f2b(__expf(acc[i][j][r] - M));
                if (r & 1) ep[i][j][r >> 1] |= ((unsigned int)eb << 16);
                else       ep[i][j][r >> 1]  = eb;
                s += b2f(eb);
            }
            sm[i][r] = s;
        }
#pragma unroll
    for (int off = 1; off < 16; off <<= 1)
#pragma unroll
        for (int i = 0; i < 4; i++)
#pragma unroll
            for (int r = 0; r < 4; r++)
                sm[i][r] += __shfl_xor(sm[i][r], off, 64);
    if (l16 == 0) {
#pragma unroll
        for (int i = 0; i < 4; i++)
#pragma unroll
            for (int r = 0; r < 4; r++)
                redS[ch * 128 + mw + i * 16 + quad * 4 + r] = sm[i][r];
    }

    // ---- stage 2 in two 64-col halves of P ----
    f32x4 acc2[4][4];
#pragma unroll
    for (int i = 0; i < 4; i++)
#pragma unroll
        for (int j = 0; j < 4; j++) { acc2[i][j][0] = 0.f; acc2[i][j][1] = 0.f; acc2[i][j][2] = 0.f; acc2[i][j][3] = 0.f; }

#pragma unroll
    for (int h = 0; h < 2; h++) {
        if ((wid >> 1) == h) {   // this wave's cols are in half h
#pragma unroll
            for (int i = 0; i < 4; i++)
#pragma unroll
                for (int j = 0; j < 4; j++)
#pragma unroll
                    for (int r = 0; r < 4; r++) {
                        int row = mw + i * 16 + quad * 4 + r;
                        int cl = j * 16 + l16;   // local col 0..63
                        unsigned short eb = (unsigned short)(ep[i][j][r >> 1] >> ((r & 1) * 16));
                        Pb[row * 64 + (((cl >> 3) ^ (row & 7)) << 3) + (cl & 7)] = eb;
                    }
        }
        __syncthreads();
#pragma unroll
        for (int ksl = 0; ksl < 2; ksl++) {
            int ks = h * 2 + ksl;
            bf16x8 af[4], bfr[4];
#pragma unroll
            for (int i = 0; i < 4; i++) {
                int row = mw + i * 16 + l16;
                af[i] = *(const bf16x8*)&Pb[row * 64 + (((ksl * 4 + quad) ^ (row & 7)) << 3)];
            }
#pragma unroll
            for (int j = 0; j < 4; j++) {
                int row = nw + j * 16 + l16;
                bfr[j] = *(const bf16x8*)&Cx[row * 128 + (((ks * 4 + quad) ^ (row & 15)) << 3)];
            }
#pragma unroll
            for (int i = 0; i < 4; i++)
#pragma unroll
                for (int j = 0; j < 4; j++)
                    acc2[i][j] = __builtin_amdgcn_mfma_f32_16x16x32_bf16(af[i], bfr[j], acc2[i][j], 0, 0, 0);
        }
        __syncthreads();
    }

    // ---- epilogue: scale by 1/rowsum, write f32 ----
#pragma unroll
    for (int i = 0; i < 4; i++)
#pragma unroll
        for (int r = 0; r < 4; r++) {
            int row = mw + i * 16 + quad * 4 + r;
            float invd = 1.f / (redS[row] + redS[128 + row]);
            float* op = out + (long)(m0 + row) * DDIM + head * 128;
#pragma unroll
            for (int j = 0; j < 4; j++)
                op[nw + j * 16 + l16] = acc2[i][j][r] * invd;
        }
}

// ---------------- softmax over N (k), fp32 in place ----------
__global__ __launch_bounds__(256) void softmax_n2(float* __restrict__ k) {
    int d0 = blockIdx.x * 16;
    int b = d0 >> 10, d = d0 & 1023;
    int col = threadIdx.x & 15, seg = threadIdx.x >> 4;
    float* p = k + (long)b * NCOND * DDIM + d + col;
    float m = -1e30f, s = 0.f;
    for (int n = seg * 32; n < seg * 32 + 32; n++) {
        float v = p[(long)n * DDIM];
        float nm = fmaxf(m, v);
        s = s * __expf(m - nm) + __expf(v - nm);
        m = nm;
    }
    __shared__ float shm[16][17], shs[16][17];
    shm[seg][col] = m; shs[seg][col] = s;
    __syncthreads();
    if (seg == 0) {
        float M = shm[0][col], S = shs[0][col];
#pragma unroll
        for (int t = 1; t < 16; t++) {
            float m2 = shm[t][col], s2 = shs[t][col];
            float nm = fmaxf(M, m2);
            S = S * __expf(M - nm) + s2 * __expf(m2 - nm);
            M = nm;
        }
        shm[0][col] = M; shs[0][col] = S;
    }
    __syncthreads();
    float M = shm[0][col], inv = 1.f / shs[0][col];
    for (int n = seg * 32; n < seg * 32 + 32; n++) {
        float v = p[(long)n * DDIM];
        p[(long)n * DDIM] = __expf(v - M) * inv;
    }
}

// ---------------- ctx_t[b,h,vv,kk] = sum_n k_sm[b,n,h,kk]*v[b,n,h,vv] -------
__global__ __launch_bounds__(256) void context_t(const float* __restrict__ k,
                                                 const float* __restrict__ v,
                                                 unsigned short* __restrict__ ctxT)
{
    int blk = blockIdx.x;
    int strip = blk & 7;
    int bh = blk >> 3;
    int b = bh >> 3, h = bh & 7;
    int c0 = strip * 16;

    __shared__ float vch[64][128];
    __shared__ float kch[64][16];

    int tid = threadIdx.x;
    int r = tid & 127;
    int cb = (tid >> 7) * 8;

    float acc[8];
#pragma unroll
    for (int j = 0; j < 8; j++) acc[j] = 0.f;

    const float* vbase = v + (long)b * NCOND * DDIM + h * HD;
    const float* kbase = k + (long)b * NCOND * DDIM + h * HD + c0;

    for (int n0 = 0; n0 < NCOND; n0 += 64) {
#pragma unroll
        for (int i = 0; i < 32; i++) {
            int e = tid + i * 256;
            int nn = e >> 7, colv = e & 127;
            vch[nn][colv] = vbase[(long)(n0 + nn) * DDIM + colv];
        }
#pragma unroll
        for (int i = 0; i < 4; i++) {
            int e = tid + i * 256;
            int nn = e >> 4, colk = e & 15;
            kch[nn][colk] = kbase[(long)(n0 + nn) * DDIM + colk];
        }
        __syncthreads();
#pragma unroll 8
        for (int nn = 0; nn < 64; nn++) {
            float vv_ = vch[nn][r];
#pragma unroll
            for (int j = 0; j < 8; j++) acc[j] += vv_ * kch[nn][cb + j];
        }
        __syncthreads();
    }
    unsigned short* cp = ctxT + ((long)bh * 128 + r) * 128 + c0 + cb;
#pragma unroll
    for (int j = 0; j < 8; j++) cp[j] = f2b(acc[j]);
}

extern "C" void kernel_launch(void* const* d_in, const int* in_sizes, int n_in,
                              void* d_out, int out_size, void* d_ws, size_t ws_size,
                              hipStream_t stream) {
    (void)in_sizes; (void)n_in; (void)out_size; (void)ws_size;
    const float* x     = (const float*)d_in[0];
    const float* cond  = (const float*)d_in[1];
    const float* ln_g  = (const float*)d_in[2];
    const float* ln_b  = (const float*)d_in[3];
    const float* tln_g = (const float*)d_in[4];
    const float* tln_b = (const float*)d_in[5];
    const float* Wq    = (const float*)d_in[6];
    const float* bq    = (const float*)d_in[7];
    const float* Wk    = (const float*)d_in[8];
    const float* bk    = (const float*)d_in[9];
    const float* Wv    = (const float*)d_in[10];
    const float* bv    = (const float*)d_in[11];
    float* out = (float*)d_out;

    uint8_t* w8 = (uint8_t*)d_ws;
    unsigned short* xn   = (unsigned short*)w8;                  // 33,554,432 B
    unsigned short* cn   = (unsigned short*)(w8 + 33554432);     //  3,145,728
    unsigned short* wqT  = (unsigned short*)(w8 + 36700160);     //  2,097,152
    unsigned short* wkvT = (unsigned short*)(w8 + 38797312);     //  3,145,728
    float*          fk   = (float*)(w8 + 41943040);              //  8,388,608
    float*          fv   = (float*)(w8 + 50331648);              //  8,388,608
    unsigned short* ctxT = (unsigned short*)(w8 + 58720256);     //  1,048,576

    ln_apply_sw<<<2048, 128, 0, stream>>>(cond, tln_g, tln_b, cn, LDIM);
    wtrans3<<<dim3(32, 32, 3), 256, 0, stream>>>(Wq, Wk, Wv, wqT, wkvT);
    ln_apply_sw<<<16384, 128, 0, stream>>>(x, ln_g, ln_b, xn, DDIM);

    // k,v = LN(cond) @ {Wk,Wv} + {bk,bv} -> f32  (M=2048, K=768, N=1024)
    gemm_bf16<64, false><<<dim3(8, 32, 2), 256, 0, stream>>>(
        cn, LDIM, wkvT, LDIM, bk, bv, fk, DDIM, LDIM, 2,
        (long long)768 * 1024, 2097152LL);

    softmax_n2<<<256, 256, 0, stream>>>(fk);
    context_t<<<256, 256, 0, stream>>>(fk, fv, ctxT);

    // fused: q-proj + softmax + @ctx -> out
    qfused<<<dim3(128, 8), 256, 0, stream>>>(xn, wqT, bq, ctxT, out);
}